// Round 7
// baseline (539.809 us; speedup 1.0000x reference)
//
#include <hip/hip_runtime.h>

// ---------------------------------------------------------------------------
// Res_NL pansharpening network, B=1, H=W=128, f32 in/out. 4 dispatches.
//   prep_k      : features 4-way output-split (256 blk) + weight slabs
//                 + pad-border zeroing + sync-flag zeroing
//   heads_k     : attention heads on MFMA (R14, verified).
//   assemble_k  : mlp combine + resu/respan; writes x f32 + padded bf16
//   convchain_k : R18: whole conv chain (3x(conv1,conv2) + recon) as ONE
//                 normal launch with a deadlock-free task queue:
//                 7x1024 tasks claimed via atomicAdd (claim order = index
//                 order -> deps always already claimed -> progress with ANY
//                 residency; no cooperative launch, no grid.sync).
//                 Row-granular deps: stage s row y waits rowcnt[s-1][y-1..y+1]
//                 ==8 (covers RAW halo + ping-pong WAR). Relaxed spins +
//                 agent acquire fence; producer: syncthreads (vmcnt drain) +
//                 agent release fence + relaxed add. Task body = R14's
//                 verified convm/convr math (16-px strips, pair-dword LDS).
//                 R17's cooperative version failed at the launch API level
//                 (out never written); this removes that API entirely.
// Activations padded [42][130][136] u16 (1-halo, 16B-aligned rows).
// ---------------------------------------------------------------------------

#define DEV __device__ __forceinline__
typedef float f32x4 __attribute__((ext_vector_type(4)));
typedef __bf16 bf16x8 __attribute__((ext_vector_type(8)));
typedef unsigned short u16;
typedef unsigned int u32;

constexpr int N = 128 * 128;

// ---- workspace layout (float offsets) -------------------------------------
constexpr int OFF_PHI1 =   0 * N;   // 3 ch
constexpr int OFF_TH1  =   3 * N;   // 3 ch
constexpr int OFF_PHI2 =   6 * N;   // 5 ch
constexpr int OFF_TH2  =  11 * N;   // 5 ch
constexpr int OFF_PHI3 =  16 * N;   // 8 ch
constexpr int OFF_TH3  =  24 * N;   // 8 ch
constexpr int OFF_G1   =  32 * N;   // 5 ch
constexpr int OFF_G2   =  37 * N;   // 5 ch
constexpr int OFF_G3   =  42 * N;   // 5 ch
constexpr int OFF_X    =  47 * N;   // 42 ch f32 (skip path)
constexpr int OFF_OH1  =  89 * N;   // 5 ch
constexpr int OFF_OH2  =  94 * N;   // 5 ch
constexpr int OFF_OH3  =  99 * N;   // 5 ch
constexpr int OFF_SLAB = 104 * N;   // u16[155648] in the 104N..110N gap
constexpr int OFF_SYNC = 109 * N;   // u32[1024]: [s*128+y] rowcnt, [896] head
constexpr int XPLANE   = 130 * 136;           // 17680 u16 per channel
constexpr int OFF_XPAD = 110 * N;
constexpr int OFF_FPAD = 133 * N;
constexpr int SLAB_CV  = 24576;               // u16 per 42-oc conv (3mt*16ks*512)
constexpr int SLAB_RC  = 6 * SLAB_CV;         // 147456 (recon offset)
constexpr int SLAB_TOT = SLAB_RC + 8192;      // 155648
constexpr int ZPB      = 656;                 // border u16 per plane (+col130)
constexpr int ZTOT     = 2 * 42 * ZPB;        // 55104
constexpr int SYNCW    = 1024;
constexpr int WPREP_TOT = SLAB_TOT + ZTOT + SYNCW;  // 211776
constexpr int WPREP_BLK = (WPREP_TOT + 255) / 256;  // 828
constexpr int NTASK    = 7 * 1024;

DEV bool inb(int y, int x) { return (unsigned)y < 128u && (unsigned)x < 128u; }
DEV u16 f2bf(float f) {
    unsigned u = __float_as_uint(f);
    return (u16)((u + 0x7fffu + ((u >> 16) & 1u)) >> 16);
}

struct PrepArgs {
    const float* u;    const float* pan;  const float* wnlu; const float* wnlpan;
    const float* gphi; const float* gth;  const float* gg;   const float* sphi;
    const float* sth;  const float* sg;   const float* mphi; const float* mth;
    const float* mg;
    const float* w[7];     // rb0w1,rb0w2,rb1w1,rb1w2,rb2w1,rb2w2,recon
};

// ---------------------------------------------------------------------------
// K1: prep. blocks 0..255: features in 4 output groups.
// blocks 256..: bf16 MFMA A-slabs + pad-border zeroing + sync zeroing.
// Slab K-permutation: k = ks*32 + quad*8 + j, with
//   g  = ks*8 + quad*2 + (j>>2)   (g = ic*3 + ty, input row id, <126 valid)
//   tx = j&3                      (window col, tx==3 -> A=0 pad)
// ---------------------------------------------------------------------------
__global__ __launch_bounds__(256) void prep_k(PrepArgs pa, float* __restrict__ ws,
                                              u16* __restrict__ slab,
                                              u16* __restrict__ xpad,
                                              u16* __restrict__ fpad,
                                              u32* __restrict__ syncb) {
    const int bid = blockIdx.x, t = threadIdx.x;
    if (bid < 256) {
        const int g = bid >> 6;
        const int p = (bid & 63) * 256 + t;
        const int y = p >> 7, x = p & 127;

        float uv[8][9];
#pragma unroll
        for (int ic = 0; ic < 8; ++ic)
#pragma unroll
            for (int i = 0; i < 3; ++i)
#pragma unroll
                for (int j = 0; j < 3; ++j) {
                    int yy = y + i - 1, xx = x + j - 1;
                    uv[ic][i * 3 + j] =
                        inb(yy, xx) ? pa.u[ic * N + yy * 128 + xx] : 0.f;
                }
        float uf[5] = {0, 0, 0, 0, 0};
#pragma unroll
        for (int ic = 0; ic < 8; ++ic)
#pragma unroll
            for (int k = 0; k < 9; ++k)
#pragma unroll
                for (int o = 0; o < 5; ++o)
                    uf[o] = fmaf(uv[ic][k], pa.wnlu[(o * 8 + ic) * 9 + k], uf[o]);

        if (g == 0) {
#pragma unroll
            for (int o = 0; o < 5; ++o) {
                float a = 0, b = 0, c1 = 0;
#pragma unroll
                for (int i = 0; i < 5; ++i) {
                    a  = fmaf(pa.sphi[o * 5 + i], uf[i], a);
                    b  = fmaf(pa.sth [o * 5 + i], uf[i], b);
                    c1 = fmaf(pa.gg  [o * 5 + i], uf[i], c1);
                }
                ws[OFF_PHI2 + o * N + p] = a;
                ws[OFF_TH2  + o * N + p] = b;
                ws[OFF_G1   + o * N + p] = c1;
            }
        } else if (g == 1) {
#pragma unroll
            for (int o = 0; o < 5; ++o) {
                float c2 = 0, c3 = 0;
#pragma unroll
                for (int i = 0; i < 5; ++i) {
                    c2 = fmaf(pa.sg[o * 5 + i], uf[i], c2);
                    c3 = fmaf(pa.mg[o * 5 + i], uf[i], c3);
                }
                ws[OFF_G2 + o * N + p] = c2;
                ws[OFF_G3 + o * N + p] = c3;
            }
        } else {
            float pv[9];
#pragma unroll
            for (int i = 0; i < 3; ++i)
#pragma unroll
                for (int j = 0; j < 3; ++j) {
                    int yy = y + i - 1, xx = x + j - 1;
                    pv[i * 3 + j] = inb(yy, xx) ? pa.pan[yy * 128 + xx] : 0.f;
                }
            float pf[3] = {0, 0, 0};
#pragma unroll
            for (int k = 0; k < 9; ++k)
#pragma unroll
                for (int o = 0; o < 3; ++o)
                    pf[o] = fmaf(pv[k], pa.wnlpan[o * 9 + k], pf[o]);
            float cat[8] = {uf[0], uf[1], uf[2], uf[3], uf[4],
                            pf[0], pf[1], pf[2]};
            if (g == 2) {
#pragma unroll
                for (int o = 0; o < 3; ++o) {
                    float a = 0, b = 0;
#pragma unroll
                    for (int i = 0; i < 3; ++i) {
                        a = fmaf(pa.gphi[o * 3 + i], pf[i], a);
                        b = fmaf(pa.gth [o * 3 + i], pf[i], b);
                    }
                    ws[OFF_PHI1 + o * N + p] = a;
                    ws[OFF_TH1  + o * N + p] = b;
                }
#pragma unroll
                for (int o = 0; o < 8; ++o) {
                    float a = 0;
#pragma unroll
                    for (int i = 0; i < 8; ++i)
                        a = fmaf(pa.mphi[o * 8 + i], cat[i], a);
                    ws[OFF_PHI3 + o * N + p] = a;
                }
            } else {
#pragma unroll
                for (int o = 0; o < 8; ++o) {
                    float b = 0;
#pragma unroll
                    for (int i = 0; i < 8; ++i)
                        b = fmaf(pa.mth[o * 8 + i], cat[i], b);
                    ws[OFF_TH3 + o * N + p] = b;
                }
            }
        }
        return;
    }

    int idx = (bid - 256) * 256 + t;
    if (idx >= WPREP_TOT) return;
    if (idx < SLAB_TOT) {
        const float* W;
        int mt, ks, lane, j, ocv;
        if (idx < SLAB_RC) {
            int cv = idx / SLAB_CV, r = idx - cv * SLAB_CV;
            mt = r / 8192;  r -= mt * 8192;
            ks = r / 512;   r -= ks * 512;
            lane = r / 8;   j = r - lane * 8;
            W = pa.w[cv]; ocv = 42;
        } else {
            int r = idx - SLAB_RC;
            mt = 0;
            ks = r / 512;   r -= ks * 512;
            lane = r / 8;   j = r - lane * 8;
            W = pa.w[6]; ocv = 8;
        }
        int quad = lane >> 4, m = lane & 15;
        int g = ks * 8 + quad * 2 + (j >> 2), tx = j & 3;
        int oc = mt * 16 + m;
        u16 v = 0;
        if (g < 126 && tx < 3 && oc < ocv) {
            int ic = g / 3, ty = g - ic * 3;
            v = f2bf(W[(oc * 42 + ic) * 9 + ty * 3 + tx]);
        }
        slab[idx] = v;
        return;
    }
    idx -= SLAB_TOT;
    if (idx < ZTOT) {
        u16* buf = (idx < 42 * ZPB) ? xpad : fpad;
        int e = (idx < 42 * ZPB) ? idx : idx - 42 * ZPB;
        int plane = e / ZPB, rem = e - plane * ZPB;
        int row, col;
        if (rem < 136)      { row = 0;             col = rem; }
        else if (rem < 272) { row = 129;           col = rem - 136; }
        else if (rem < 400) { row = 1 + rem - 272; col = 0; }
        else if (rem < 528) { row = 1 + rem - 400; col = 129; }
        else                { row = 1 + rem - 528; col = 130; }
        buf[plane * XPLANE + row * 136 + col] = 0;
        return;
    }
    idx -= ZTOT;
    syncb[idx] = 0;     // idx < 1024: rowcnt[7][128] + task head
}

// ---------------------------------------------------------------------------
// K2: attention heads via MFMA (R14, verified). Block = one 8x8 px tile.
// ---------------------------------------------------------------------------
template <int C, int P>
DEV void head_mfma(const float* __restrict__ phi, const float* __restrict__ theta,
                   const float* __restrict__ g, float* __restrict__ oh,
                   u16* __restrict__ sB, float* __restrict__ sG,
                   int ty0, int tx0, int t) {
    constexpr int D  = C * P * P;            // 27 / 5 / 72
    constexpr int KC = (D + 31) / 32;        // 1 / 1 / 3
    constexpr int K  = KC * 32;
    constexpr int SK = K + 8;                // padded row stride (u16)

    for (int i = t; i < 5 * 196; i += 256) {
        int c = i / 196, rem = i - c * 196;
        int r = rem / 14, cc = rem - r * 14;
        int gy = ty0 - 3 + r, gx = tx0 - 3 + cc;
        sG[i] = inb(gy, gx) ? g[c * N + gy * 128 + gx] : 0.f;
    }

    if (t < 224) {
        int r = t >> 4, cc = t & 15;
        int gy0 = ty0 - 3 + r, gx0 = tx0 - 3 + cc;
        union { uint4 u[K / 8]; u16 s[K]; } rb;
#pragma unroll
        for (int k = 0; k < K; ++k) {
            float v = 0.f;
            if (cc < 14 && k < D) {
                int c, dy, dx;
                if (P == 3) {
                    c = k / 9; int tau = k - c * 9;
                    dy = tau / 3 - 1; dx = tau - (tau / 3) * 3 - 1;
                } else { c = k; dy = 0; dx = 0; }
                int yy = gy0 + dy, xx = gx0 + dx;
                v = inb(yy, xx) ? phi[c * N + yy * 128 + xx] : 0.f;
            }
            rb.s[k] = f2bf(v);
        }
        u16* dst = sB + t * SK;
#pragma unroll
        for (int q = 0; q < K / 8; ++q)
            *(uint4*)(dst + q * 8) = rb.u[q];
    }

    const int lane = t & 63, wave = t >> 6;
    const int og = lane >> 4, cp = lane & 15;
    const int mA = wave * 16 + cp;
    const int gyA = ty0 + (mA >> 3), gxA = tx0 + (mA & 7);
    union ABu { uint4 u; u16 s[8]; bf16x8 b; };
    ABu afr[KC];
#pragma unroll
    for (int kc = 0; kc < KC; ++kc)
#pragma unroll
        for (int j = 0; j < 8; ++j) {
            int k = kc * 32 + og * 8 + j;
            float v = 0.f;
            if (k < D) {
                int c, dy, dx;
                if (P == 3) {
                    c = k / 9; int tau = k - c * 9;
                    dy = tau / 3 - 1; dx = tau - (tau / 3) * 3 - 1;
                } else { c = k; dy = 0; dx = 0; }
                int yy = gyA + dy, xx = gxA + dx;
                v = inb(yy, xx) ? theta[c * N + yy * 128 + xx] : 0.f;
            }
            afr[kc].s[j] = f2bf(v);
        }
    __syncthreads();

    f32x4 acc[14];
#pragma unroll
    for (int nc = 0; nc < 14; ++nc) acc[nc] = (f32x4){0.f, 0.f, 0.f, 0.f};
    const u16* sBl = sB + cp * SK + og * 8;
#pragma unroll
    for (int nc = 0; nc < 14; ++nc)
#pragma unroll
        for (int kc = 0; kc < KC; ++kc) {
            ABu bf_;
            bf_.u = *(const uint4*)(sBl + nc * 16 * SK + kc * 32);
            acc[nc] = __builtin_amdgcn_mfma_f32_16x16x32_bf16(
                afr[kc].b, bf_.b, acc[nc], 0, 0, 0);
        }

    float mx[4], sum[4];
#pragma unroll
    for (int reg = 0; reg < 4; ++reg) {
        int midx = wave * 16 + og * 4 + reg;
        int py = midx >> 3, px = midx & 7;
        bool colok = (unsigned)(cp - px) < 7u;
        float m0 = -3.0e38f;
#pragma unroll
        for (int nc = 0; nc < 14; ++nc) {
            bool valid = colok && (unsigned)(nc - py) < 7u;
            if (valid) m0 = fmaxf(m0, acc[nc][reg]);
        }
        mx[reg] = m0;
    }
#pragma unroll
    for (int reg = 0; reg < 4; ++reg) {
        mx[reg] = fmaxf(mx[reg], __shfl_xor(mx[reg], 1));
        mx[reg] = fmaxf(mx[reg], __shfl_xor(mx[reg], 2));
        mx[reg] = fmaxf(mx[reg], __shfl_xor(mx[reg], 4));
        mx[reg] = fmaxf(mx[reg], __shfl_xor(mx[reg], 8));
    }
#pragma unroll
    for (int reg = 0; reg < 4; ++reg) {
        int midx = wave * 16 + og * 4 + reg;
        int py = midx >> 3, px = midx & 7;
        bool colok = (unsigned)(cp - px) < 7u;
        float s0 = 0.f;
#pragma unroll
        for (int nc = 0; nc < 14; ++nc) {
            bool valid = colok && (unsigned)(nc - py) < 7u;
            float e = valid ? __expf(acc[nc][reg] - mx[reg]) : 0.f;
            acc[nc][reg] = e;
            s0 += e;
        }
        sum[reg] = s0;
    }
#pragma unroll
    for (int reg = 0; reg < 4; ++reg) {
        sum[reg] += __shfl_xor(sum[reg], 1);
        sum[reg] += __shfl_xor(sum[reg], 2);
        sum[reg] += __shfl_xor(sum[reg], 4);
        sum[reg] += __shfl_xor(sum[reg], 8);
    }

    float o0[5][4];
#pragma unroll
    for (int ch = 0; ch < 5; ++ch)
#pragma unroll
        for (int reg = 0; reg < 4; ++reg) o0[ch][reg] = 0.f;
#pragma unroll
    for (int ch = 0; ch < 5; ++ch)
#pragma unroll
        for (int nc = 0; nc < 14; ++nc) {
            float gvv = (cp < 14) ? sG[ch * 196 + nc * 14 + cp] : 0.f;
#pragma unroll
            for (int reg = 0; reg < 4; ++reg)
                o0[ch][reg] = fmaf(acc[nc][reg], gvv, o0[ch][reg]);
        }
#pragma unroll
    for (int ch = 0; ch < 5; ++ch)
#pragma unroll
        for (int reg = 0; reg < 4; ++reg) {
            o0[ch][reg] += __shfl_xor(o0[ch][reg], 1);
            o0[ch][reg] += __shfl_xor(o0[ch][reg], 2);
            o0[ch][reg] += __shfl_xor(o0[ch][reg], 4);
            o0[ch][reg] += __shfl_xor(o0[ch][reg], 8);
        }

    if (cp < 5) {
        float inv[4];
#pragma unroll
        for (int reg = 0; reg < 4; ++reg) inv[reg] = 1.f / sum[reg];
#pragma unroll
        for (int ch = 0; ch < 5; ++ch)
            if (cp == ch) {
#pragma unroll
                for (int reg = 0; reg < 4; ++reg) {
                    int midx = wave * 16 + og * 4 + reg;
                    int gy = ty0 + (midx >> 3), gx = tx0 + (midx & 7);
                    oh[ch * N + gy * 128 + gx] = o0[ch][reg] * inv[reg];
                }
            }
    }
}

__global__ __launch_bounds__(256) void heads_k(float* __restrict__ ws) {
    __shared__ u16 smem[25256];          // sB 224*104 u16 + sG 980 f32 = 50512B
    u16* sB = smem;
    float* sG = (float*)(smem + 23296);
    const int t = threadIdx.x;
    const int ty0 = (blockIdx.x >> 4) * 8, tx0 = (blockIdx.x & 15) * 8;
    if (blockIdx.y == 0)
        head_mfma<3, 3>(ws + OFF_PHI1, ws + OFF_TH1, ws + OFF_G1, ws + OFF_OH1,
                        sB, sG, ty0, tx0, t);
    else if (blockIdx.y == 1)
        head_mfma<5, 1>(ws + OFF_PHI2, ws + OFF_TH2, ws + OFF_G2, ws + OFF_OH2,
                        sB, sG, ty0, tx0, t);
    else
        head_mfma<8, 3>(ws + OFF_PHI3, ws + OFF_TH3, ws + OFF_G3, ws + OFF_OH3,
                        sB, sG, ty0, tx0, t);
}

// ---------------------------------------------------------------------------
// K3: assemble, grid (64, 5). Writes x f32 (skip) + padded bf16 (MFMA input).
// ---------------------------------------------------------------------------
__global__ __launch_bounds__(256, 2) void assemble_k(
    const float* __restrict__ u, const float* __restrict__ pan,
    const float* __restrict__ wres, const float* __restrict__ wrp,
    const float* __restrict__ mlpw, const float* __restrict__ mlpb,
    float* __restrict__ ws, u16* __restrict__ xpad) {
    const int p = blockIdx.x * 256 + threadIdx.x;
    const int y = p >> 7, x = p & 127;
    const int padp = (y + 1) * 136 + (x + 1);
    float* xb = ws + OFF_X;

    if (blockIdx.y == 0) {
        const float w0 = mlpw[0], w1 = mlpw[1], w2 = mlpw[2];
        const float bb = mlpb[0];
#pragma unroll
        for (int c = 0; c < 5; ++c) {
            float a = ws[OFF_OH1 + c * N + p] * w0 +
                      ws[OFF_OH2 + c * N + p] * w1 +
                      ws[OFF_OH3 + c * N + p] * w2 + bb;
            xb[c * N + p] = a;
            xpad[c * XPLANE + padp] = f2bf(a);
        }
        float pv[9];
#pragma unroll
        for (int i = 0; i < 3; ++i)
#pragma unroll
            for (int j = 0; j < 3; ++j) {
                int yy = y + i - 1, xx = x + j - 1;
                pv[i * 3 + j] = inb(yy, xx) ? pan[yy * 128 + xx] : 0.f;
            }
        float a5[5] = {0, 0, 0, 0, 0};
#pragma unroll
        for (int k = 0; k < 9; ++k)
#pragma unroll
            for (int o = 0; o < 5; ++o)
                a5[o] = fmaf(pv[k], wrp[o * 9 + k], a5[o]);
#pragma unroll
        for (int o = 0; o < 5; ++o) {
            xb[(37 + o) * N + p] = a5[o];
            xpad[(37 + o) * XPLANE + padp] = f2bf(a5[o]);
        }
    } else {
        const int ob = (blockIdx.y - 1) * 8;
        float uv[8][9];
#pragma unroll
        for (int ic = 0; ic < 8; ++ic)
#pragma unroll
            for (int i = 0; i < 3; ++i)
#pragma unroll
                for (int j = 0; j < 3; ++j) {
                    int yy = y + i - 1, xx = x + j - 1;
                    uv[ic][i * 3 + j] =
                        inb(yy, xx) ? u[ic * N + yy * 128 + xx] : 0.f;
                }
        float acc[8] = {0, 0, 0, 0, 0, 0, 0, 0};
#pragma unroll
        for (int ic = 0; ic < 8; ++ic)
#pragma unroll
            for (int k = 0; k < 9; ++k)
#pragma unroll
                for (int o = 0; o < 8; ++o)
                    acc[o] = fmaf(uv[ic][k], wres[((ob + o) * 8 + ic) * 9 + k],
                                  acc[o]);
#pragma unroll
        for (int o = 0; o < 8; ++o) {
            xb[(5 + ob + o) * N + p] = acc[o];
            xpad[(5 + ob + o) * XPLANE + padp] = f2bf(acc[o]);
        }
    }
}

// ---------------------------------------------------------------------------
// K4 (R18): task-queue conv chain. Task = (stage s 0..6, tile tl 0..1023),
// tile = 16 px of one row (y=tl>>3, x0=(tl&7)<<4). Stages 0..5: conv
// (even: xpad->fpad, odd: fpad->xpad + skip xf32); stage 6: recon -> out.
// Body = R14's verified convm/convr math.
// ---------------------------------------------------------------------------
struct ChainArgs {
    u16* xpad; u16* fpad; const u16* slab;
    const float* bias[6];
    float* xf32; float* out; u32* sync;
};

DEV void stage_tile(const u16* xin, u32* sXp, int t, int y, int x0) {
    const u16* srcbase = xin + y * 136 + x0;   // pad rows y..y+2 = img y-1..y+1
#pragma unroll
    for (int it = 0; it < 2; ++it) {
        int c = it * 192 + t;
        if (c < 378) {                         // 126 rows * 3 slots
            int row = c / 3, slot = c - row * 3;
            int ic = row / 3, r = row - ic * 3;
            const u16* sp = srcbase + ic * XPLANE + r * 136 + slot * 8;
            uint4 v = *(const uint4*)sp;
            u32 nxt = (slot < 2) ? (u32)sp[8] : 0u;
            u32 d0 = v.x, d1 = v.y, d2 = v.z, d3 = v.w;
            uint4 w0, w1;
            w0.x = d0; w0.y = (d0 >> 16) | (d1 << 16);
            w0.z = d1; w0.w = (d1 >> 16) | (d2 << 16);
            w1.x = d2; w1.y = (d2 >> 16) | (d3 << 16);
            w1.z = d3; w1.w = (d3 >> 16) | (nxt << 16);
            u32* dst = sXp + row * 24 + slot * 8;
            *(uint4*)dst = w0;
            *(uint4*)(dst + 4) = w1;
        }
    }
}

__global__ __launch_bounds__(192, 3) void convchain_k(ChainArgs ca) {
    __shared__ __align__(16) u32 sXp[3072];    // 128 g-rows x 24 pair-dwords
    __shared__ u32 sTask;
    const int t = threadIdx.x;
    if (t < 48) sXp[3024 + t] = 0;             // pad rows g=126,127: never
                                               // written by stage_tile
    const int lane = t & 63, mt = t >> 6;
    const int quad = lane >> 4, col = lane & 15;

    for (;;) {
        if (t == 0) {
            u32 task = __hip_atomic_fetch_add(ca.sync + 896, 1u,
                           __ATOMIC_RELAXED, __HIP_MEMORY_SCOPE_AGENT);
            if (task < (u32)NTASK) {
                int s = (int)(task >> 10);
                if (s > 0) {
                    int y = (int)((task & 1023u) >> 3);
                    int y0 = y > 0 ? y - 1 : 0;
                    int y1 = y < 127 ? y + 1 : 127;
                    for (int yr = y0; yr <= y1; ++yr) {
                        u32* c = ca.sync + (s - 1) * 128 + yr;
                        while (__hip_atomic_load(c, __ATOMIC_RELAXED,
                                   __HIP_MEMORY_SCOPE_AGENT) < 8u)
                            __builtin_amdgcn_s_sleep(1);
                    }
                }
                __builtin_amdgcn_fence(__ATOMIC_ACQUIRE, "agent");
            }
            sTask = task;
        }
        __syncthreads();
        const u32 task = sTask;
        if (task >= (u32)NTASK) return;        // uniform exit
        const int s = (int)(task >> 10), tl = (int)(task & 1023u);
        const int y = tl >> 3, x0 = (tl & 7) << 4;
        const bool odd = (s & 1) != 0;
        const u16* src = odd ? ca.fpad : ca.xpad;   // s==6 even -> xpad

        stage_tile(src, sXp, t, y, x0);

        union AB { uint4 u; bf16x8 b; };
        if (s < 6) {
            const u16* slab = ca.slab + s * SLAB_CV;
            const float* bs = ca.bias[s];
            u16* opad = odd ? ca.xpad : ca.fpad;
            AB a[16];
#pragma unroll
            for (int ks = 0; ks < 16; ++ks)
                a[ks].u = ((const uint4*)slab)[(mt * 16 + ks) * 64 + lane];
            __syncthreads();

            const u32* bb = sXp + quad * 48 + col;
            f32x4 acc = {0.f, 0.f, 0.f, 0.f};
#pragma unroll
            for (int ks = 0; ks < 16; ++ks) {
                union { uint4 u; bf16x8 b; } bv;
                const u32* pb = bb + ks * 192;
                bv.u.x = pb[0]; bv.u.y = pb[2];
                bv.u.z = pb[24]; bv.u.w = pb[26];
                acc = __builtin_amdgcn_mfma_f32_16x16x32_bf16(a[ks].b, bv.b,
                                                              acc, 0, 0, 0);
            }
            const int xg = x0 + col;
            const int px = y * 128 + xg;
            const int padp = (y + 1) * 136 + (xg + 1);
#pragma unroll
            for (int reg = 0; reg < 4; ++reg) {
                int oc = mt * 16 + quad * 4 + reg;
                if (oc < 42) {
                    float v = acc[reg] + bs[oc];
                    if (odd) v += ca.xf32[oc * N + px];
                    v = fmaxf(v, 0.f);
                    if (odd) ca.xf32[oc * N + px] = v;
                    opad[oc * XPLANE + padp] = f2bf(v);
                }
            }
        } else {
            AB a[16];
            if (mt == 0) {
#pragma unroll
                for (int ks = 0; ks < 16; ++ks)
                    a[ks].u =
                        ((const uint4*)(ca.slab + SLAB_RC))[ks * 64 + lane];
            }
            __syncthreads();
            if (mt == 0) {
                const u32* bb = sXp + quad * 48 + col;
                f32x4 acc = {0.f, 0.f, 0.f, 0.f};
#pragma unroll
                for (int ks = 0; ks < 16; ++ks) {
                    union { uint4 u; bf16x8 b; } bv;
                    const u32* pb = bb + ks * 192;
                    bv.u.x = pb[0]; bv.u.y = pb[2];
                    bv.u.z = pb[24]; bv.u.w = pb[26];
                    acc = __builtin_amdgcn_mfma_f32_16x16x32_bf16(
                        a[ks].b, bv.b, acc, 0, 0, 0);
                }
                const int px = y * 128 + x0 + col;
#pragma unroll
                for (int reg = 0; reg < 4; ++reg) {
                    int oc = quad * 4 + reg;
                    if (oc < 8) ca.out[oc * N + px] = acc[reg];
                }
            }
        }

        __syncthreads();                       // all stores done, vmcnt drained
        if (t == 0) {
            __builtin_amdgcn_fence(__ATOMIC_RELEASE, "agent");
            __hip_atomic_fetch_add(ca.sync + s * 128 + y, 1u,
                                   __ATOMIC_RELAXED, __HIP_MEMORY_SCOPE_AGENT);
        }
    }
}

// ---------------------------------------------------------------------------
extern "C" void kernel_launch(void* const* d_in, const int* in_sizes, int n_in,
                              void* d_out, int out_size, void* d_ws, size_t ws_size,
                              hipStream_t stream) {
    (void)in_sizes; (void)n_in; (void)out_size; (void)ws_size;
    float* ws = (float*)d_ws;
    float* out = (float*)d_out;

    PrepArgs pa;
    pa.u      = (const float*)d_in[0];
    pa.pan    = (const float*)d_in[1];
    pa.wnlu   = (const float*)d_in[2];
    pa.wnlpan = (const float*)d_in[3];
    pa.gphi   = (const float*)d_in[4];
    pa.gth    = (const float*)d_in[5];
    pa.gg     = (const float*)d_in[6];
    pa.sphi   = (const float*)d_in[7];
    pa.sth    = (const float*)d_in[8];
    pa.sg     = (const float*)d_in[9];
    pa.mphi   = (const float*)d_in[10];
    pa.mth    = (const float*)d_in[11];
    pa.mg     = (const float*)d_in[12];
    pa.w[0]   = (const float*)d_in[18];
    pa.w[1]   = (const float*)d_in[20];
    pa.w[2]   = (const float*)d_in[22];
    pa.w[3]   = (const float*)d_in[24];
    pa.w[4]   = (const float*)d_in[26];
    pa.w[5]   = (const float*)d_in[28];
    pa.w[6]   = (const float*)d_in[17];   // recon

    const float* mlpw = (const float*)d_in[13];
    const float* mlpb = (const float*)d_in[14];
    const float* wres = (const float*)d_in[15];
    const float* wrp  = (const float*)d_in[16];

    u16* xpad = (u16*)(ws + OFF_XPAD);
    u16* fpad = (u16*)(ws + OFF_FPAD);
    u16* slab = (u16*)(ws + OFF_SLAB);
    u32* syncb = (u32*)(ws + OFF_SYNC);

    prep_k<<<256 + WPREP_BLK, 256, 0, stream>>>(pa, ws, slab, xpad, fpad,
                                                syncb);
    heads_k<<<dim3(256, 3), 256, 0, stream>>>(ws);
    assemble_k<<<dim3(64, 5), 256, 0, stream>>>(pa.u, pa.pan, wres, wrp, mlpw,
                                                mlpb, ws, xpad);

    ChainArgs ca;
    ca.xpad = xpad; ca.fpad = fpad; ca.slab = slab;
    ca.bias[0] = (const float*)d_in[19]; ca.bias[1] = (const float*)d_in[21];
    ca.bias[2] = (const float*)d_in[23]; ca.bias[3] = (const float*)d_in[25];
    ca.bias[4] = (const float*)d_in[27]; ca.bias[5] = (const float*)d_in[29];
    ca.xf32 = ws + OFF_X; ca.out = out; ca.sync = syncb;
    convchain_k<<<1024, 192, 0, stream>>>(ca);
}

// Round 8
// 211.397 us; speedup vs baseline: 2.5535x; 2.5535x over previous
//
#include <hip/hip_runtime.h>

// ---------------------------------------------------------------------------
// Res_NL pansharpening network, B=1, H=W=128, f32 in/out. 10 dispatches
// (R14 structure — best measured 209us. R15-R18 structural fusions all lost:
// halo-fusion 246-255us, coop-launch failed, task-queue 540us. The serial
// dispatch chain is the floor-setter; per-kernel tuning only from here).
//   prep_k     : features 4-way output-split (256 blk) + weight slabs
//                + pad-border zeroing
//   heads_k    : attention heads on MFMA (R14). Per 8x8-px tile:
//                S[64][224] = thp(64xK') x php(K'x224), softmax in C-layout,
//                scalar PV + shfl reduce.
//   assemble_k : mlp combine + resu/respan; writes x f32 + padded bf16
//   convm_k    : implicit-GEMM conv, 1024 blk x 192 thr (16-px strips,
//                3 waves = 3 oc-tiles). R19: A-slab/bias/skip loads hoisted
//                BEFORE the staging barrier (G7 — they were serialized
//                behind __syncthreads and at the epilogue tail).
//   convr_k    : recon conv 42->8 (512x128, pair-dword), same hoist.
// Activations padded [42][130][136] u16 (1-halo, 16B-aligned rows).
// ---------------------------------------------------------------------------

#define DEV __device__ __forceinline__
typedef float f32x4 __attribute__((ext_vector_type(4)));
typedef __bf16 bf16x8 __attribute__((ext_vector_type(8)));
typedef unsigned short u16;
typedef unsigned int u32;

constexpr int N = 128 * 128;

// ---- workspace layout (float offsets) -------------------------------------
constexpr int OFF_PHI1 =   0 * N;   // 3 ch
constexpr int OFF_TH1  =   3 * N;   // 3 ch
constexpr int OFF_PHI2 =   6 * N;   // 5 ch
constexpr int OFF_TH2  =  11 * N;   // 5 ch
constexpr int OFF_PHI3 =  16 * N;   // 8 ch
constexpr int OFF_TH3  =  24 * N;   // 8 ch
constexpr int OFF_G1   =  32 * N;   // 5 ch
constexpr int OFF_G2   =  37 * N;   // 5 ch
constexpr int OFF_G3   =  42 * N;   // 5 ch
constexpr int OFF_X    =  47 * N;   // 42 ch f32 (skip path)
constexpr int OFF_OH1  =  89 * N;   // 5 ch
constexpr int OFF_OH2  =  94 * N;   // 5 ch
constexpr int OFF_OH3  =  99 * N;   // 5 ch
constexpr int OFF_SLAB = 104 * N;   // u16[155648] in the 104N..110N gap
constexpr int XPLANE   = 130 * 136;           // 17680 u16 per channel
constexpr int OFF_XPAD = 110 * N;
constexpr int OFF_FPAD = 133 * N;
constexpr int SLAB_CV  = 24576;               // u16 per 42-oc conv (3mt*16ks*512)
constexpr int SLAB_RC  = 6 * SLAB_CV;         // 147456 (recon offset)
constexpr int SLAB_TOT = SLAB_RC + 8192;      // 155648
constexpr int ZPB      = 656;                 // border u16 per plane (+col130)
constexpr int ZTOT     = 2 * 42 * ZPB;        // 55104
constexpr int WPREP_TOT = SLAB_TOT + ZTOT;    // 210752
constexpr int WPREP_BLK = (WPREP_TOT + 255) / 256; // 824

DEV bool inb(int y, int x) { return (unsigned)y < 128u && (unsigned)x < 128u; }
DEV u16 f2bf(float f) {
    unsigned u = __float_as_uint(f);
    return (u16)((u + 0x7fffu + ((u >> 16) & 1u)) >> 16);
}

struct PrepArgs {
    const float* u;    const float* pan;  const float* wnlu; const float* wnlpan;
    const float* gphi; const float* gth;  const float* gg;   const float* sphi;
    const float* sth;  const float* sg;   const float* mphi; const float* mth;
    const float* mg;
    const float* w[7];     // rb0w1,rb0w2,rb1w1,rb1w2,rb2w1,rb2w2,recon
};

// ---------------------------------------------------------------------------
// K1: prep. blocks 0..255: features in 4 output groups.
// blocks 256..: bf16 MFMA A-slabs + pad-border zeroing.
// Slab K-permutation: k = ks*32 + quad*8 + j, with
//   g  = ks*8 + quad*2 + (j>>2)   (g = ic*3 + ty, input row id, <126 valid)
//   tx = j&3                      (window col, tx==3 -> A=0 pad)
// ---------------------------------------------------------------------------
__global__ __launch_bounds__(256) void prep_k(PrepArgs pa, float* __restrict__ ws,
                                              u16* __restrict__ slab,
                                              u16* __restrict__ xpad,
                                              u16* __restrict__ fpad) {
    const int bid = blockIdx.x, t = threadIdx.x;
    if (bid < 256) {
        const int g = bid >> 6;
        const int p = (bid & 63) * 256 + t;
        const int y = p >> 7, x = p & 127;

        float uv[8][9];
#pragma unroll
        for (int ic = 0; ic < 8; ++ic)
#pragma unroll
            for (int i = 0; i < 3; ++i)
#pragma unroll
                for (int j = 0; j < 3; ++j) {
                    int yy = y + i - 1, xx = x + j - 1;
                    uv[ic][i * 3 + j] =
                        inb(yy, xx) ? pa.u[ic * N + yy * 128 + xx] : 0.f;
                }
        float uf[5] = {0, 0, 0, 0, 0};
#pragma unroll
        for (int ic = 0; ic < 8; ++ic)
#pragma unroll
            for (int k = 0; k < 9; ++k)
#pragma unroll
                for (int o = 0; o < 5; ++o)
                    uf[o] = fmaf(uv[ic][k], pa.wnlu[(o * 8 + ic) * 9 + k], uf[o]);

        if (g == 0) {
#pragma unroll
            for (int o = 0; o < 5; ++o) {
                float a = 0, b = 0, c1 = 0;
#pragma unroll
                for (int i = 0; i < 5; ++i) {
                    a  = fmaf(pa.sphi[o * 5 + i], uf[i], a);
                    b  = fmaf(pa.sth [o * 5 + i], uf[i], b);
                    c1 = fmaf(pa.gg  [o * 5 + i], uf[i], c1);
                }
                ws[OFF_PHI2 + o * N + p] = a;
                ws[OFF_TH2  + o * N + p] = b;
                ws[OFF_G1   + o * N + p] = c1;
            }
        } else if (g == 1) {
#pragma unroll
            for (int o = 0; o < 5; ++o) {
                float c2 = 0, c3 = 0;
#pragma unroll
                for (int i = 0; i < 5; ++i) {
                    c2 = fmaf(pa.sg[o * 5 + i], uf[i], c2);
                    c3 = fmaf(pa.mg[o * 5 + i], uf[i], c3);
                }
                ws[OFF_G2 + o * N + p] = c2;
                ws[OFF_G3 + o * N + p] = c3;
            }
        } else {
            float pv[9];
#pragma unroll
            for (int i = 0; i < 3; ++i)
#pragma unroll
                for (int j = 0; j < 3; ++j) {
                    int yy = y + i - 1, xx = x + j - 1;
                    pv[i * 3 + j] = inb(yy, xx) ? pa.pan[yy * 128 + xx] : 0.f;
                }
            float pf[3] = {0, 0, 0};
#pragma unroll
            for (int k = 0; k < 9; ++k)
#pragma unroll
                for (int o = 0; o < 3; ++o)
                    pf[o] = fmaf(pv[k], pa.wnlpan[o * 9 + k], pf[o]);
            float cat[8] = {uf[0], uf[1], uf[2], uf[3], uf[4],
                            pf[0], pf[1], pf[2]};
            if (g == 2) {
#pragma unroll
                for (int o = 0; o < 3; ++o) {
                    float a = 0, b = 0;
#pragma unroll
                    for (int i = 0; i < 3; ++i) {
                        a = fmaf(pa.gphi[o * 3 + i], pf[i], a);
                        b = fmaf(pa.gth [o * 3 + i], pf[i], b);
                    }
                    ws[OFF_PHI1 + o * N + p] = a;
                    ws[OFF_TH1  + o * N + p] = b;
                }
#pragma unroll
                for (int o = 0; o < 8; ++o) {
                    float a = 0;
#pragma unroll
                    for (int i = 0; i < 8; ++i)
                        a = fmaf(pa.mphi[o * 8 + i], cat[i], a);
                    ws[OFF_PHI3 + o * N + p] = a;
                }
            } else {
#pragma unroll
                for (int o = 0; o < 8; ++o) {
                    float b = 0;
#pragma unroll
                    for (int i = 0; i < 8; ++i)
                        b = fmaf(pa.mth[o * 8 + i], cat[i], b);
                    ws[OFF_TH3 + o * N + p] = b;
                }
            }
        }
        return;
    }

    int idx = (bid - 256) * 256 + t;
    if (idx >= WPREP_TOT) return;
    if (idx < SLAB_TOT) {
        const float* W;
        int mt, ks, lane, j, ocv;
        if (idx < SLAB_RC) {
            int cv = idx / SLAB_CV, r = idx - cv * SLAB_CV;
            mt = r / 8192;  r -= mt * 8192;
            ks = r / 512;   r -= ks * 512;
            lane = r / 8;   j = r - lane * 8;
            W = pa.w[cv]; ocv = 42;
        } else {
            int r = idx - SLAB_RC;
            mt = 0;
            ks = r / 512;   r -= ks * 512;
            lane = r / 8;   j = r - lane * 8;
            W = pa.w[6]; ocv = 8;
        }
        int quad = lane >> 4, m = lane & 15;
        int g = ks * 8 + quad * 2 + (j >> 2), tx = j & 3;
        int oc = mt * 16 + m;
        u16 v = 0;
        if (g < 126 && tx < 3 && oc < ocv) {
            int ic = g / 3, ty = g - ic * 3;
            v = f2bf(W[(oc * 42 + ic) * 9 + ty * 3 + tx]);
        }
        slab[idx] = v;
        return;
    }
    idx -= SLAB_TOT;
    u16* buf = (idx < 42 * ZPB) ? xpad : fpad;
    int e = (idx < 42 * ZPB) ? idx : idx - 42 * ZPB;
    int plane = e / ZPB, rem = e - plane * ZPB;
    int row, col;
    if (rem < 136)      { row = 0;             col = rem; }
    else if (rem < 272) { row = 129;           col = rem - 136; }
    else if (rem < 400) { row = 1 + rem - 272; col = 0; }
    else if (rem < 528) { row = 1 + rem - 400; col = 129; }
    else                { row = 1 + rem - 528; col = 130; }
    buf[plane * XPLANE + row * 136 + col] = 0;
}

// ---------------------------------------------------------------------------
// K2: attention heads via MFMA (R14, verified). Block = one 8x8 px tile.
// ---------------------------------------------------------------------------
template <int C, int P>
DEV void head_mfma(const float* __restrict__ phi, const float* __restrict__ theta,
                   const float* __restrict__ g, float* __restrict__ oh,
                   u16* __restrict__ sB, float* __restrict__ sG,
                   int ty0, int tx0, int t) {
    constexpr int D  = C * P * P;            // 27 / 5 / 72
    constexpr int KC = (D + 31) / 32;        // 1 / 1 / 3
    constexpr int K  = KC * 32;
    constexpr int SK = K + 8;                // padded row stride (u16)

    for (int i = t; i < 5 * 196; i += 256) {
        int c = i / 196, rem = i - c * 196;
        int r = rem / 14, cc = rem - r * 14;
        int gy = ty0 - 3 + r, gx = tx0 - 3 + cc;
        sG[i] = inb(gy, gx) ? g[c * N + gy * 128 + gx] : 0.f;
    }

    if (t < 224) {
        int r = t >> 4, cc = t & 15;
        int gy0 = ty0 - 3 + r, gx0 = tx0 - 3 + cc;
        union { uint4 u[K / 8]; u16 s[K]; } rb;
#pragma unroll
        for (int k = 0; k < K; ++k) {
            float v = 0.f;
            if (cc < 14 && k < D) {
                int c, dy, dx;
                if (P == 3) {
                    c = k / 9; int tau = k - c * 9;
                    dy = tau / 3 - 1; dx = tau - (tau / 3) * 3 - 1;
                } else { c = k; dy = 0; dx = 0; }
                int yy = gy0 + dy, xx = gx0 + dx;
                v = inb(yy, xx) ? phi[c * N + yy * 128 + xx] : 0.f;
            }
            rb.s[k] = f2bf(v);
        }
        u16* dst = sB + t * SK;
#pragma unroll
        for (int q = 0; q < K / 8; ++q)
            *(uint4*)(dst + q * 8) = rb.u[q];
    }

    const int lane = t & 63, wave = t >> 6;
    const int og = lane >> 4, cp = lane & 15;
    const int mA = wave * 16 + cp;
    const int gyA = ty0 + (mA >> 3), gxA = tx0 + (mA & 7);
    union ABu { uint4 u; u16 s[8]; bf16x8 b; };
    ABu afr[KC];
#pragma unroll
    for (int kc = 0; kc < KC; ++kc)
#pragma unroll
        for (int j = 0; j < 8; ++j) {
            int k = kc * 32 + og * 8 + j;
            float v = 0.f;
            if (k < D) {
                int c, dy, dx;
                if (P == 3) {
                    c = k / 9; int tau = k - c * 9;
                    dy = tau / 3 - 1; dx = tau - (tau / 3) * 3 - 1;
                } else { c = k; dy = 0; dx = 0; }
                int yy = gyA + dy, xx = gxA + dx;
                v = inb(yy, xx) ? theta[c * N + yy * 128 + xx] : 0.f;
            }
            afr[kc].s[j] = f2bf(v);
        }
    __syncthreads();

    f32x4 acc[14];
#pragma unroll
    for (int nc = 0; nc < 14; ++nc) acc[nc] = (f32x4){0.f, 0.f, 0.f, 0.f};
    const u16* sBl = sB + cp * SK + og * 8;
#pragma unroll
    for (int nc = 0; nc < 14; ++nc)
#pragma unroll
        for (int kc = 0; kc < KC; ++kc) {
            ABu bf_;
            bf_.u = *(const uint4*)(sBl + nc * 16 * SK + kc * 32);
            acc[nc] = __builtin_amdgcn_mfma_f32_16x16x32_bf16(
                afr[kc].b, bf_.b, acc[nc], 0, 0, 0);
        }

    float mx[4], sum[4];
#pragma unroll
    for (int reg = 0; reg < 4; ++reg) {
        int midx = wave * 16 + og * 4 + reg;
        int py = midx >> 3, px = midx & 7;
        bool colok = (unsigned)(cp - px) < 7u;
        float m0 = -3.0e38f;
#pragma unroll
        for (int nc = 0; nc < 14; ++nc) {
            bool valid = colok && (unsigned)(nc - py) < 7u;
            if (valid) m0 = fmaxf(m0, acc[nc][reg]);
        }
        mx[reg] = m0;
    }
#pragma unroll
    for (int reg = 0; reg < 4; ++reg) {
        mx[reg] = fmaxf(mx[reg], __shfl_xor(mx[reg], 1));
        mx[reg] = fmaxf(mx[reg], __shfl_xor(mx[reg], 2));
        mx[reg] = fmaxf(mx[reg], __shfl_xor(mx[reg], 4));
        mx[reg] = fmaxf(mx[reg], __shfl_xor(mx[reg], 8));
    }
#pragma unroll
    for (int reg = 0; reg < 4; ++reg) {
        int midx = wave * 16 + og * 4 + reg;
        int py = midx >> 3, px = midx & 7;
        bool colok = (unsigned)(cp - px) < 7u;
        float s0 = 0.f;
#pragma unroll
        for (int nc = 0; nc < 14; ++nc) {
            bool valid = colok && (unsigned)(nc - py) < 7u;
            float e = valid ? __expf(acc[nc][reg] - mx[reg]) : 0.f;
            acc[nc][reg] = e;
            s0 += e;
        }
        sum[reg] = s0;
    }
#pragma unroll
    for (int reg = 0; reg < 4; ++reg) {
        sum[reg] += __shfl_xor(sum[reg], 1);
        sum[reg] += __shfl_xor(sum[reg], 2);
        sum[reg] += __shfl_xor(sum[reg], 4);
        sum[reg] += __shfl_xor(sum[reg], 8);
    }

    float o0[5][4];
#pragma unroll
    for (int ch = 0; ch < 5; ++ch)
#pragma unroll
        for (int reg = 0; reg < 4; ++reg) o0[ch][reg] = 0.f;
#pragma unroll
    for (int ch = 0; ch < 5; ++ch)
#pragma unroll
        for (int nc = 0; nc < 14; ++nc) {
            float gvv = (cp < 14) ? sG[ch * 196 + nc * 14 + cp] : 0.f;
#pragma unroll
            for (int reg = 0; reg < 4; ++reg)
                o0[ch][reg] = fmaf(acc[nc][reg], gvv, o0[ch][reg]);
        }
#pragma unroll
    for (int ch = 0; ch < 5; ++ch)
#pragma unroll
        for (int reg = 0; reg < 4; ++reg) {
            o0[ch][reg] += __shfl_xor(o0[ch][reg], 1);
            o0[ch][reg] += __shfl_xor(o0[ch][reg], 2);
            o0[ch][reg] += __shfl_xor(o0[ch][reg], 4);
            o0[ch][reg] += __shfl_xor(o0[ch][reg], 8);
        }

    if (cp < 5) {
        float inv[4];
#pragma unroll
        for (int reg = 0; reg < 4; ++reg) inv[reg] = 1.f / sum[reg];
#pragma unroll
        for (int ch = 0; ch < 5; ++ch)
            if (cp == ch) {
#pragma unroll
                for (int reg = 0; reg < 4; ++reg) {
                    int midx = wave * 16 + og * 4 + reg;
                    int gy = ty0 + (midx >> 3), gx = tx0 + (midx & 7);
                    oh[ch * N + gy * 128 + gx] = o0[ch][reg] * inv[reg];
                }
            }
    }
}

__global__ __launch_bounds__(256) void heads_k(float* __restrict__ ws) {
    __shared__ u16 smem[25256];          // sB 224*104 u16 + sG 980 f32 = 50512B
    u16* sB = smem;
    float* sG = (float*)(smem + 23296);
    const int t = threadIdx.x;
    const int ty0 = (blockIdx.x >> 4) * 8, tx0 = (blockIdx.x & 15) * 8;
    if (blockIdx.y == 0)
        head_mfma<3, 3>(ws + OFF_PHI1, ws + OFF_TH1, ws + OFF_G1, ws + OFF_OH1,
                        sB, sG, ty0, tx0, t);
    else if (blockIdx.y == 1)
        head_mfma<5, 1>(ws + OFF_PHI2, ws + OFF_TH2, ws + OFF_G2, ws + OFF_OH2,
                        sB, sG, ty0, tx0, t);
    else
        head_mfma<8, 3>(ws + OFF_PHI3, ws + OFF_TH3, ws + OFF_G3, ws + OFF_OH3,
                        sB, sG, ty0, tx0, t);
}

// ---------------------------------------------------------------------------
// K3: assemble, grid (64, 5). Writes x f32 (skip) + padded bf16 (MFMA input).
// ---------------------------------------------------------------------------
__global__ __launch_bounds__(256, 2) void assemble_k(
    const float* __restrict__ u, const float* __restrict__ pan,
    const float* __restrict__ wres, const float* __restrict__ wrp,
    const float* __restrict__ mlpw, const float* __restrict__ mlpb,
    float* __restrict__ ws, u16* __restrict__ xpad) {
    const int p = blockIdx.x * 256 + threadIdx.x;
    const int y = p >> 7, x = p & 127;
    const int padp = (y + 1) * 136 + (x + 1);
    float* xb = ws + OFF_X;

    if (blockIdx.y == 0) {
        const float w0 = mlpw[0], w1 = mlpw[1], w2 = mlpw[2];
        const float bb = mlpb[0];
#pragma unroll
        for (int c = 0; c < 5; ++c) {
            float a = ws[OFF_OH1 + c * N + p] * w0 +
                      ws[OFF_OH2 + c * N + p] * w1 +
                      ws[OFF_OH3 + c * N + p] * w2 + bb;
            xb[c * N + p] = a;
            xpad[c * XPLANE + padp] = f2bf(a);
        }
        float pv[9];
#pragma unroll
        for (int i = 0; i < 3; ++i)
#pragma unroll
            for (int j = 0; j < 3; ++j) {
                int yy = y + i - 1, xx = x + j - 1;
                pv[i * 3 + j] = inb(yy, xx) ? pan[yy * 128 + xx] : 0.f;
            }
        float a5[5] = {0, 0, 0, 0, 0};
#pragma unroll
        for (int k = 0; k < 9; ++k)
#pragma unroll
            for (int o = 0; o < 5; ++o)
                a5[o] = fmaf(pv[k], wrp[o * 9 + k], a5[o]);
#pragma unroll
        for (int o = 0; o < 5; ++o) {
            xb[(37 + o) * N + p] = a5[o];
            xpad[(37 + o) * XPLANE + padp] = f2bf(a5[o]);
        }
    } else {
        const int ob = (blockIdx.y - 1) * 8;
        float uv[8][9];
#pragma unroll
        for (int ic = 0; ic < 8; ++ic)
#pragma unroll
            for (int i = 0; i < 3; ++i)
#pragma unroll
                for (int j = 0; j < 3; ++j) {
                    int yy = y + i - 1, xx = x + j - 1;
                    uv[ic][i * 3 + j] =
                        inb(yy, xx) ? u[ic * N + yy * 128 + xx] : 0.f;
                }
        float acc[8] = {0, 0, 0, 0, 0, 0, 0, 0};
#pragma unroll
        for (int ic = 0; ic < 8; ++ic)
#pragma unroll
            for (int k = 0; k < 9; ++k)
#pragma unroll
                for (int o = 0; o < 8; ++o)
                    acc[o] = fmaf(uv[ic][k], wres[((ob + o) * 8 + ic) * 9 + k],
                                  acc[o]);
#pragma unroll
        for (int o = 0; o < 8; ++o) {
            xb[(5 + ob + o) * N + p] = acc[o];
            xpad[(5 + ob + o) * XPLANE + padp] = f2bf(acc[o]);
        }
    }
}

// ---------------------------------------------------------------------------
// K4: implicit-GEMM conv on MFMA, padded bf16 input. Block = 16 px of one
// row, 192 threads = 3 waves (wave = oc-tile mt), grid 1024, 4 blocks/CU.
// Pair-dword LDS tile [128 g-rows][24], B-frag {0,2,24,26} + ks*192.
// R19: slab A-frags + bias + skip loaded BEFORE the barrier (latency hides
// under staging drain; was serialized after it).
// ---------------------------------------------------------------------------
template <bool SKIP, bool WF32, bool WPAD>
__global__ __launch_bounds__(192, 3) void convm_k(
    const u16* __restrict__ xin, const u16* __restrict__ slab,
    const float* __restrict__ bs, const float* __restrict__ skip,
    float* __restrict__ of32, u16* __restrict__ opad) {
    __shared__ __align__(16) u32 sXp[3072];   // 128 rows x 24 pair-dwords
    const int t = threadIdx.x;
    const int y = blockIdx.x >> 3, x0 = (blockIdx.x & 7) << 4;

    const u16* srcbase = xin + y * 136 + x0;   // pad rows y..y+2 = img y-1..y+1
#pragma unroll
    for (int it = 0; it < 2; ++it) {
        int c = it * 192 + t;
        if (c < 378) {                         // 126 rows * 3 slots
            int row = c / 3, slot = c - row * 3;
            int ic = row / 3, r = row - ic * 3;
            const u16* sp = srcbase + ic * XPLANE + r * 136 + slot * 8;
            uint4 v = *(const uint4*)sp;
            u32 nxt = (slot < 2) ? (u32)sp[8] : 0u;
            u32 d0 = v.x, d1 = v.y, d2 = v.z, d3 = v.w;
            uint4 w0, w1;
            w0.x = d0; w0.y = (d0 >> 16) | (d1 << 16);
            w0.z = d1; w0.w = (d1 >> 16) | (d2 << 16);
            w1.x = d2; w1.y = (d2 >> 16) | (d3 << 16);
            w1.z = d3; w1.w = (d3 >> 16) | (nxt << 16);
            u32* dst = sXp + row * 24 + slot * 8;
            *(uint4*)dst = w0;
            *(uint4*)(dst + 4) = w1;
        }
    }
    if (t < 48) sXp[3024 + t] = 0;             // g=126,127 pad rows

    const int lane = t & 63, mt = t >> 6;
    const int quad = lane >> 4, col = lane & 15;
    const int xg = x0 + col;
    const int px = y * 128 + xg;
    const int padp = (y + 1) * 136 + (xg + 1);
    const int ocb = mt * 16 + quad * 4;

    union AB { uint4 u; bf16x8 b; };
    AB a[16];
#pragma unroll
    for (int ks = 0; ks < 16; ++ks)
        a[ks].u = ((const uint4*)slab)[(mt * 16 + ks) * 64 + lane];

    float b4[4], sk4[4];
#pragma unroll
    for (int reg = 0; reg < 4; ++reg) {
        int oc = ocb + reg;
        b4[reg]  = (oc < 42) ? bs[oc] : 0.f;
        if (SKIP) sk4[reg] = (oc < 42) ? skip[oc * N + px] : 0.f;
    }

    __syncthreads();

    const u32* bb = sXp + quad * 48 + col;
    f32x4 acc = {0.f, 0.f, 0.f, 0.f};
#pragma unroll
    for (int ks = 0; ks < 16; ++ks) {
        union { uint4 u; bf16x8 b; } bv;
        const u32* pb = bb + ks * 192;
        bv.u.x = pb[0]; bv.u.y = pb[2]; bv.u.z = pb[24]; bv.u.w = pb[26];
        acc = __builtin_amdgcn_mfma_f32_16x16x32_bf16(a[ks].b, bv.b, acc,
                                                      0, 0, 0);
    }

#pragma unroll
    for (int reg = 0; reg < 4; ++reg) {
        int oc = ocb + reg;
        if (oc < 42) {
            float v = acc[reg] + b4[reg];
            if (SKIP) v += sk4[reg];
            v = fmaxf(v, 0.f);
            if (WF32) of32[oc * N + px] = v;
            if (WPAD) opad[oc * XPLANE + padp] = f2bf(v);
        }
    }
}

// ---------------------------------------------------------------------------
// K5: recon conv 42->8, padded bf16 input, 32-px strips (grid 512, 128 thr).
// Pair-dword scheme, stride 40, mt=0. R19: A-frags loaded pre-barrier.
// ---------------------------------------------------------------------------
__global__ __launch_bounds__(128, 1) void convr_k(
    const u16* __restrict__ xin, const u16* __restrict__ slab,
    float* __restrict__ out) {
    __shared__ __align__(16) u32 sXp[5120];
    const int t = threadIdx.x;
    const int y = blockIdx.x >> 2, x0 = (blockIdx.x & 3) << 5;

    const u16* srcbase = xin + y * 136 + x0;
#pragma unroll
    for (int it = 0; it < 5; ++it) {
        int c = it * 128 + t;
        if (c < 630) {
            int row = c / 5, slot = c - row * 5;
            int ic = row / 3, r = row - ic * 3;
            const u16* sp = srcbase + ic * XPLANE + r * 136 + slot * 8;
            uint4 v = *(const uint4*)sp;
            u32 nxt = sp[8];
            u32 d0 = v.x, d1 = v.y, d2 = v.z, d3 = v.w;
            uint4 w0, w1;
            w0.x = d0; w0.y = (d0 >> 16) | (d1 << 16);
            w0.z = d1; w0.w = (d1 >> 16) | (d2 << 16);
            w1.x = d2; w1.y = (d2 >> 16) | (d3 << 16);
            w1.z = d3; w1.w = (d3 >> 16) | (nxt << 16);
            u32* dst = sXp + row * 40 + slot * 8;
            *(uint4*)dst = w0;
            *(uint4*)(dst + 4) = w1;
        }
    }
    if (t < 80) sXp[5040 + t] = 0;

    const int lane = t & 63, wave = t >> 6;
    const int quad = lane >> 4, col = lane & 15;
    const int ncol = wave * 16 + col;

    union AB { uint4 u; bf16x8 b; };
    AB a[16];
#pragma unroll
    for (int ks = 0; ks < 16; ++ks)
        a[ks].u = ((const uint4*)slab)[ks * 64 + lane];

    __syncthreads();

    const u32* bb = sXp + quad * 80 + ncol;
    f32x4 acc = {0.f, 0.f, 0.f, 0.f};
#pragma unroll
    for (int ks = 0; ks < 16; ++ks) {
        union { uint4 u; bf16x8 b; } bv;
        const u32* pb = bb + ks * 320;
        bv.u.x = pb[0]; bv.u.y = pb[2]; bv.u.z = pb[40]; bv.u.w = pb[42];
        acc = __builtin_amdgcn_mfma_f32_16x16x32_bf16(a[ks].b, bv.b, acc,
                                                      0, 0, 0);
    }
    const int px = y * 128 + x0 + ncol;
#pragma unroll
    for (int reg = 0; reg < 4; ++reg) {
        int oc = quad * 4 + reg;
        if (oc < 8) out[oc * N + px] = acc[reg];
    }
}

// ---------------------------------------------------------------------------
extern "C" void kernel_launch(void* const* d_in, const int* in_sizes, int n_in,
                              void* d_out, int out_size, void* d_ws, size_t ws_size,
                              hipStream_t stream) {
    (void)in_sizes; (void)n_in; (void)out_size; (void)ws_size;
    float* ws = (float*)d_ws;
    float* out = (float*)d_out;

    PrepArgs pa;
    pa.u      = (const float*)d_in[0];
    pa.pan    = (const float*)d_in[1];
    pa.wnlu   = (const float*)d_in[2];
    pa.wnlpan = (const float*)d_in[3];
    pa.gphi   = (const float*)d_in[4];
    pa.gth    = (const float*)d_in[5];
    pa.gg     = (const float*)d_in[6];
    pa.sphi   = (const float*)d_in[7];
    pa.sth    = (const float*)d_in[8];
    pa.sg     = (const float*)d_in[9];
    pa.mphi   = (const float*)d_in[10];
    pa.mth    = (const float*)d_in[11];
    pa.mg     = (const float*)d_in[12];
    pa.w[0]   = (const float*)d_in[18];
    pa.w[1]   = (const float*)d_in[20];
    pa.w[2]   = (const float*)d_in[22];
    pa.w[3]   = (const float*)d_in[24];
    pa.w[4]   = (const float*)d_in[26];
    pa.w[5]   = (const float*)d_in[28];
    pa.w[6]   = (const float*)d_in[17];   // recon

    const float* mlpw = (const float*)d_in[13];
    const float* mlpb = (const float*)d_in[14];
    const float* wres = (const float*)d_in[15];
    const float* wrp  = (const float*)d_in[16];

    u16* xpad = (u16*)(ws + OFF_XPAD);
    u16* fpad = (u16*)(ws + OFF_FPAD);
    u16* slab = (u16*)(ws + OFF_SLAB);

    prep_k<<<256 + WPREP_BLK, 256, 0, stream>>>(pa, ws, slab, xpad, fpad);
    heads_k<<<dim3(256, 3), 256, 0, stream>>>(ws);
    assemble_k<<<dim3(64, 5), 256, 0, stream>>>(pa.u, pa.pan, wres, wrp, mlpw,
                                                mlpb, ws, xpad);

    for (int r = 0; r < 3; ++r) {
        const float* b1 = (const float*)d_in[19 + 4 * r];
        const float* b2 = (const float*)d_in[21 + 4 * r];
        convm_k<false, false, true>
            <<<1024, 192, 0, stream>>>(xpad, slab + (2 * r) * SLAB_CV, b1,
                                       nullptr, nullptr, fpad);
        convm_k<true, true, true>
            <<<1024, 192, 0, stream>>>(fpad, slab + (2 * r + 1) * SLAB_CV, b2,
                                       ws + OFF_X, ws + OFF_X, xpad);
    }
    convr_k<<<512, 128, 0, stream>>>(xpad, slab + SLAB_RC, out);
}